// Round 11
// baseline (201.808 us; speedup 1.0000x reference)
//
#include <hip/hip_runtime.h>
#include <hip/hip_bf16.h>

#define B_  2
#define S_  2048
#define D_  1024
#define H_  16
#define DK_ 64
#define M_  (B_ * S_)   // 4096

typedef short short8 __attribute__((ext_vector_type(8)));
typedef float float4v __attribute__((ext_vector_type(4)));

// log2(e)/8 : folded into Q at projection so attention exp is a bare v_exp_f32
#define QSCALE 0.18033688011112042f

static __device__ __forceinline__ ushort f32_to_bf16bits(float f) {
    union { __hip_bfloat16 h; ushort u; } cv;
    cv.h = __float2bfloat16(f);
    return cv.u;
}

// async global->LDS, 16B per lane (lands at wave-uniform base + lane*16)
static __device__ __forceinline__ void glds16(const ushort* g, ushort* l) {
    __builtin_amdgcn_global_load_lds(
        (const __attribute__((address_space(1))) unsigned int*)g,
        (__attribute__((address_space(3))) unsigned int*)l, 16, 0, 0);
}

// ---------------------------------------------------------------------------
// prep: z in [0,3) -> transpose+convert W_z[k][n] fp32 -> Wt[n][k] bf16
//       z in [3,11) -> convert X fp32 -> bf16
// ---------------------------------------------------------------------------
__global__ __launch_bounds__(256) void prep(
    const float* __restrict__ X, const float* __restrict__ W0,
    const float* __restrict__ W1, const float* __restrict__ W2,
    ushort* __restrict__ Xb, ushort* __restrict__ Wt)
{
    const int z = blockIdx.z;
    const int t = threadIdx.x;

    if (z >= 3) {   // convert X
        const int blk = (z - 3) * 256 + blockIdx.y * 16 + blockIdx.x;
        const int i = blk * 2048 + t * 8;
        float4v a = *(const float4v*)(X + i);
        float4v b = *(const float4v*)(X + i + 4);
        short8 o;
        o[0] = (short)f32_to_bf16bits(a[0]); o[1] = (short)f32_to_bf16bits(a[1]);
        o[2] = (short)f32_to_bf16bits(a[2]); o[3] = (short)f32_to_bf16bits(a[3]);
        o[4] = (short)f32_to_bf16bits(b[0]); o[5] = (short)f32_to_bf16bits(b[1]);
        o[6] = (short)f32_to_bf16bits(b[2]); o[7] = (short)f32_to_bf16bits(b[3]);
        *(short8*)(Xb + i) = o;
        return;
    }

    const float* W = (z == 0) ? W0 : ((z == 1) ? W1 : W2);
    ushort* out = Wt + (size_t)z * D_ * D_;

    __shared__ ushort tile[64 * 72];
    int n0 = blockIdx.x * 64, k0 = blockIdx.y * 64;
    int r = t >> 3, g = t & 7;

    #pragma unroll
    for (int p = 0; p < 2; ++p) {
        int rr = r + p * 32;
        const float* src = W + (size_t)(k0 + rr) * D_ + n0 + g * 8;
        float4v a = *(const float4v*)src;
        float4v b = *(const float4v*)(src + 4);
        short8 o;
        o[0] = (short)f32_to_bf16bits(a[0]); o[1] = (short)f32_to_bf16bits(a[1]);
        o[2] = (short)f32_to_bf16bits(a[2]); o[3] = (short)f32_to_bf16bits(a[3]);
        o[4] = (short)f32_to_bf16bits(b[0]); o[5] = (short)f32_to_bf16bits(b[1]);
        o[6] = (short)f32_to_bf16bits(b[2]); o[7] = (short)f32_to_bf16bits(b[3]);
        *(short8*)&tile[rr * 72 + g * 8] = o;
    }
    __syncthreads();
    #pragma unroll
    for (int p = 0; p < 2; ++p) {
        int rr = r + p * 32;
        short8 v;
        #pragma unroll
        for (int i = 0; i < 8; ++i)
            v[i] = (short)tile[(g * 8 + i) * 72 + rr];
        *(short8*)(out + (size_t)(n0 + rr) * D_ + k0 + g * 8) = v;
    }
}

// ---------------------------------------------------------------------------
// FUSED-z QKV projection: one block = (m-tile 64, n-tile 128) computing q, k
// AND v.  A staged once, 48 MFMA per barrier.  56 KB LDS = 2 blocks/CU.
// k/v work skipped (block-uniform) when this m-tile is beyond length[b].
// z==0 (Q) epilogue folds score-scale*log2(e) into the values.
// ---------------------------------------------------------------------------
__global__ __launch_bounds__(256, 2) void proj_gemm(
    const ushort* __restrict__ X,    // [4096][1024] bf16
    const ushort* __restrict__ Wt,   // [3][1024][1024] bf16, n-major
    const float* __restrict__ b0, const float* __restrict__ b1,
    const float* __restrict__ b2,
    const int* __restrict__ length,
    ushort* __restrict__ qkv)        // [3][4M] bf16
{
    const int m0 = blockIdx.x * 64, n0 = blockIdx.y * 128;
    const int bidx = m0 >> 11;
    const int s0 = m0 & (S_ - 1);
    const bool kv = (s0 < length[bidx]);   // block-uniform

    __shared__ __align__(16) ushort As[64 * 64];        //  8 KB
    __shared__ __align__(16) ushort Bs[3][128 * 64];    // 48 KB

    const int t = threadIdx.x;
    const int lane = t & 63, wid = t >> 6;
    const int quad = lane >> 4, l16 = lane & 15;
    const int wr = wid >> 1, wc = wid & 1;

    float4v accq[2][4] = {}, acck[2][4] = {}, accv[2][4] = {};

    for (int kt = 0; kt < 16; ++kt) {
        const int k0 = kt * 64;
        __syncthreads();
        #pragma unroll
        for (int j = 0; j < 2; ++j) {          // A: 512 chunks, 128/wave
            const int cid = wid * 128 + j * 64 + lane;
            const int row = cid >> 3;
            const int cl  = (cid & 7) ^ (row & 7);
            glds16(X + (size_t)(m0 + row) * D_ + k0 + cl * 8, &As[cid * 8]);
        }
        #pragma unroll
        for (int j = 0; j < 4; ++j) {          // B panels: 1024 chunks each
            const int cid = wid * 256 + j * 64 + lane;
            const int row = cid >> 3;
            const int cl  = (cid & 7) ^ (row & 7);
            const size_t off = (size_t)(n0 + row) * D_ + k0 + cl * 8;
            glds16(Wt + off, &Bs[0][cid * 8]);
            if (kv) {
                glds16(Wt + (size_t)D_ * D_ + off,     &Bs[1][cid * 8]);
                glds16(Wt + (size_t)2 * D_ * D_ + off, &Bs[2][cid * 8]);
            }
        }
        __syncthreads();

        #pragma unroll
        for (int ks = 0; ks < 2; ++ks) {
            short8 a[2];
            #pragma unroll
            for (int i = 0; i < 2; ++i) {
                const int r = wr * 32 + i * 16 + l16;
                const int ph = (ks * 4 + quad) ^ (r & 7);
                a[i] = *(short8*)&As[r * 64 + ph * 8];
            }
            short8 bq[4];
            #pragma unroll
            for (int j = 0; j < 4; ++j) {
                const int r = wc * 64 + j * 16 + l16;
                const int ph = (ks * 4 + quad) ^ (r & 7);
                bq[j] = *(short8*)&Bs[0][r * 64 + ph * 8];
            }
            #pragma unroll
            for (int i = 0; i < 2; ++i)
                #pragma unroll
                for (int j = 0; j < 4; ++j)
                    accq[i][j] = __builtin_amdgcn_mfma_f32_16x16x32_bf16(
                        a[i], bq[j], accq[i][j], 0, 0, 0);
            if (kv) {
                short8 bk[4], bv[4];
                #pragma unroll
                for (int j = 0; j < 4; ++j) {
                    const int r = wc * 64 + j * 16 + l16;
                    const int ph = (ks * 4 + quad) ^ (r & 7);
                    bk[j] = *(short8*)&Bs[1][r * 64 + ph * 8];
                    bv[j] = *(short8*)&Bs[2][r * 64 + ph * 8];
                }
                #pragma unroll
                for (int i = 0; i < 2; ++i)
                    #pragma unroll
                    for (int j = 0; j < 4; ++j) {
                        acck[i][j] = __builtin_amdgcn_mfma_f32_16x16x32_bf16(
                            a[i], bk[j], acck[i][j], 0, 0, 0);
                        accv[i][j] = __builtin_amdgcn_mfma_f32_16x16x32_bf16(
                            a[i], bv[j], accv[i][j], 0, 0, 0);
                    }
            }
        }
    }

    // epilogue: +bias, scatter into head layouts.
    #pragma unroll
    for (int j = 0; j < 4; ++j) {
        const int col = n0 + wc * 64 + j * 16 + l16;
        const int h = col >> 6, dk = col & (DK_ - 1);
        const float bvq = b0[col], bvk = b1[col], bvv = b2[col];
        #pragma unroll
        for (int i = 0; i < 2; ++i) {
            #pragma unroll
            for (int rr = 0; rr < 4; ++rr) {
                const int row = m0 + wr * 32 + i * 16 + quad * 4 + rr;
                const int s = row & (S_ - 1);
                const size_t hdr = ((size_t)(bidx * H_ + h) * S_ + s) * DK_ + dk;
                qkv[hdr] = f32_to_bf16bits((accq[i][j][rr] + bvq) * QSCALE);
                if (kv) {
                    qkv[(size_t)M_ * D_ + hdr] =
                        f32_to_bf16bits(acck[i][j][rr] + bvk);
                    qkv[(size_t)2 * M_ * D_ +
                        ((size_t)(bidx * H_ + h) * DK_ + dk) * S_ + s] =
                        f32_to_bf16bits(accv[i][j][rr] + bvv);
                }
            }
        }
    }
}

// ---------------------------------------------------------------------------
// attention v10 = v7 (register-P via PV-aligned K-row permutation, Q in regs,
// T4 counted-vmcnt K pipeline, XCD swizzle, balanced (h,b,qblk) decode,
// 64 q-rows/block; NO setprio) + ONE change: V never touches LDS either.
// The PV B-operand fragment is CONTIGUOUS in global V[dk][key] storage:
// lane (quad,l16) needs V[key=ks*32+quad*8+j][dk=ct*16+l16] = 16B at
// vb + (ct*16+l16)*S + kt*64 + ks*32 + quad*8.  Load it per-lane, issued
// right after the barrier (pinned BEFORE the K-stage glds so the compiler's
// pre-PV wait is vmcnt(2), keeping the K prefetch in flight); ~200cy L2
// latency hides under QK+exp.  V tile is L2-resident (32 q-blocks of the
// same head per XCD share it -- the swizzle's doing).  Effects: PV's LDS
// dependency deleted from the critical chain; LDS traffic halves (K only);
// LDS 48 -> 24 KB, launch_bounds(256,4) -> 4 blocks/CU (16 waves).
// vmcnt discipline (2 glds per K-stage): top wait vmcnt(2) (last iter 0);
// K(kt+1) is drained by the compiler's pre-PV V-wait in iter kt (V is newer
// than K(kt+1), older than K(kt+2)).  Verified for nkt=1,2 edge cases.
// ---------------------------------------------------------------------------
__global__ __launch_bounds__(256, 4) void attention(
    const ushort* __restrict__ qkv, const int* __restrict__ length,
    float* __restrict__ out)
{
    // XCD-chunk swizzle: 1024 blocks, 8 XCDs, 128 works/XCD (bijective).
    const int bid  = blockIdx.x;
    const int work = (bid & 7) * 128 + (bid >> 3);
    const int q0 = (work & 31) * 64;
    const int bh = work >> 5;          // 0..31
    const int b  = bh & 1;
    const int h  = bh >> 1;

    int len = length[b];
    if (len > S_) len = S_;
    if (len < 1) len = 1;
    const int nkt = (len + 63) >> 6;

    const ushort* qb = qkv + ((size_t)(b * H_ + h) * S_ + q0) * DK_;
    const ushort* kb = qkv + (size_t)M_ * D_ + (size_t)(b * H_ + h) * S_ * DK_;
    const ushort* vb = qkv + (size_t)2 * M_ * D_ + (size_t)(b * H_ + h) * DK_ * S_;

    __shared__ __align__(16) ushort Ks[3][64 * 64];    // 24 KB [key][dk], hash hK

    const int t = threadIdx.x, lane = t & 63, wid = t >> 6;
    const int quad = lane >> 4, l16 = lane & 15;

    // K read-side constants: krow = kbase[ct] + klocal; hK(krow) = hk (per-lane)
    const int klocal = ((l16 >> 2) << 3) + (l16 & 3);
    const int hk     = (l16 & 3) | (((l16 >> 2) & 1) << 2);

    // Q fragments: straight from global, no LDS.
    short8 qfrag[2];
    {
        const ushort* qp = qb + (size_t)(wid * 16 + l16) * DK_;
        qfrag[0] = *(const short8*)(qp + quad * 8);
        qfrag[1] = *(const short8*)(qp + (4 + quad) * 8);
    }

    // stage K tile -> buffer buf (2 glds per wave: vmcnt ticks in 2s)
    auto stageK = [&](int buf, int tile) {
        #pragma unroll
        for (int j = 0; j < 2; ++j) {
            const int cid = wid * 128 + j * 64 + lane;
            const int row = cid >> 3;
            const int c   = cid & 7;
            const int hKr = (row & 3) | (((row >> 3) & 1) << 2);
            glds16(kb + (size_t)(tile * 64 + row) * DK_ + (c ^ hKr) * 8,
                   &Ks[buf][cid * 8]);
        }
    };

    // prologue: prefetch K tiles 0 and 1
    stageK(0, 0);
    if (nkt > 1) stageK(1, 1);

    // bf16 ones fragment for the rowsum MFMA
    short8 ones8;
    #pragma unroll
    for (int i = 0; i < 8; ++i) ones8[i] = (short)0x3F80;

    float4v cacc[4] = {};
    float4v racc = {};

    int cur = 0;
    for (int kt = 0; kt < nkt; ++kt) {
        // Ks[cur] complete (K(kt) was drained by iter kt-1's pre-PV V-wait;
        // iter 0 / nkt==1 handled by the counted/zero wait here).
        if (kt == nkt - 1) {
            asm volatile("s_waitcnt vmcnt(0) lgkmcnt(0)" ::: "memory");
        } else {
            asm volatile("s_waitcnt vmcnt(2) lgkmcnt(0)" ::: "memory");
        }
        __builtin_amdgcn_sched_barrier(0);
        __builtin_amdgcn_s_barrier();
        __builtin_amdgcn_sched_barrier(0);

        // V fragments: per-lane direct loads, issued FIRST (oldest) so the
        // compiler's pre-PV wait leaves the K-stage glds in flight.
        short8 vfrag[2][4];
        #pragma unroll
        for (int ks = 0; ks < 2; ++ks)
            #pragma unroll
            for (int ct = 0; ct < 4; ++ct)
                vfrag[ks][ct] = *(const short8*)(
                    vb + (size_t)(ct * 16 + l16) * S_ + kt * 64 + ks * 32 + quad * 8);
        __builtin_amdgcn_sched_barrier(0);

        // prefetch K tile kt+2 into the buffer all waves just finished reading
        if (kt + 2 < nkt) {
            int sb = cur + 2; if (sb >= 3) sb -= 3;
            stageK(sb, kt + 2);
        }
        __builtin_amdgcn_sched_barrier(0);

        // S^T with PV-aligned K-row permutation.  Lane (quad,l16) holds
        // sacc[ct][rr] = S[key=(ct>>1)*32+quad*8+(ct&1)*4+rr][q=l16].
        float4v sacc[4] = {};
        #pragma unroll
        for (int ks = 0; ks < 2; ++ks) {
            #pragma unroll
            for (int ct = 0; ct < 4; ++ct) {
                const int krow = ((ct >> 1) << 5) + ((ct & 1) << 2) + klocal;
                const int pha = (ks * 4 + quad) ^ hk;
                short8 ak = *(short8*)&Ks[cur][krow * 64 + pha * 8];
                sacc[ct] = __builtin_amdgcn_mfma_f32_16x16x32_bf16(
                    ak, qfrag[ks], sacc[ct], 0, 0, 0);
            }
        }

        // exp2 + (boundary-only) mask + truncation-pack -> PV A-frags in regs
        const bool full = ((kt + 1) * 64 <= len);
        short8 ap[2];
        #pragma unroll
        for (int ks = 0; ks < 2; ++ks) {
            union { uint u[4]; short8 s; } cv;
            #pragma unroll
            for (int hh = 0; hh < 2; ++hh) {
                const int ct = 2 * ks + hh;
                float e0 = __builtin_amdgcn_exp2f(sacc[ct][0]);
                float e1 = __builtin_amdgcn_exp2f(sacc[ct][1]);
                float e2 = __builtin_amdgcn_exp2f(sacc[ct][2]);
                float e3 = __builtin_amdgcn_exp2f(sacc[ct][3]);
                if (!full) {
                    const int kb0 = kt * 64 + ks * 32 + quad * 8 + hh * 4;
                    e0 = (kb0 + 0 < len) ? e0 : 0.f;
                    e1 = (kb0 + 1 < len) ? e1 : 0.f;
                    e2 = (kb0 + 2 < len) ? e2 : 0.f;
                    e3 = (kb0 + 3 < len) ? e3 : 0.f;
                }
                cv.u[hh * 2 + 0] = (__float_as_uint(e0) >> 16) |
                                   (__float_as_uint(e1) & 0xFFFF0000u);
                cv.u[hh * 2 + 1] = (__float_as_uint(e2) >> 16) |
                                   (__float_as_uint(e3) & 0xFFFF0000u);
            }
            ap[ks] = cv.s;
        }

        // P @ V  (+ rowsum via ones-MFMA, reusing ap).  P and V both in
        // registers -- PV issues with no LDS dependency.  The compiler's
        // vmcnt wait for vfrag (vmcnt(2)) keeps the K prefetch in flight.
        #pragma unroll
        for (int ks = 0; ks < 2; ++ks) {
            #pragma unroll
            for (int ct = 0; ct < 4; ++ct) {
                cacc[ct] = __builtin_amdgcn_mfma_f32_16x16x32_bf16(
                    ap[ks], vfrag[ks][ct], cacc[ct], 0, 0, 0);
            }
            racc = __builtin_amdgcn_mfma_f32_16x16x32_bf16(
                ap[ks], ones8, racc, 0, 0, 0);
        }

        cur = cur + 1; if (cur == 3) cur = 0;
    }

    // normalize + store fp32.  racc[rr] holds rowsum for q = quad*4+rr in
    // every l16 lane -- exactly where cacc[ct][rr] needs it.  No shuffles.
    #pragma unroll
    for (int rr = 0; rr < 4; ++rr) {
        const float inv = 1.0f / (racc[rr] + 1e-8f);
        const int q = q0 + wid * 16 + quad * 4 + rr;
        #pragma unroll
        for (int ct = 0; ct < 4; ++ct) {
            const int d = h * 64 + ct * 16 + l16;
            out[((size_t)b * S_ + q) * D_ + d] = cacc[ct][rr] * inv;
        }
    }
}

// ---------------------------------------------------------------------------
extern "C" void kernel_launch(void* const* d_in, const int* in_sizes, int n_in,
                              void* d_out, int out_size, void* d_ws, size_t ws_size,
                              hipStream_t stream)
{
    const float* Q   = (const float*)d_in[0];
    const int*   len = (const int*)d_in[1];
    const float* Wq  = (const float*)d_in[2];
    const float* bq  = (const float*)d_in[3];
    const float* Wk  = (const float*)d_in[4];
    const float* bk  = (const float*)d_in[5];
    const float* Wv  = (const float*)d_in[6];
    const float* bv  = (const float*)d_in[7];
    float* out = (float*)d_out;

    ushort* ws  = (ushort*)d_ws;
    ushort* Xb  = ws;                                   // 4M bf16 = 8 MB
    ushort* Wt  = ws + (size_t)M_ * D_;                 // 3M bf16 = 6 MB
    ushort* qkv = Wt + (size_t)3 * D_ * D_;             // 12M bf16 = 24 MB

    dim3 gPr(16, 16, 11);
    prep<<<gPr, 256, 0, stream>>>(Q, Wq, Wk, Wv, Xb, Wt);

    dim3 gP(M_ / 64, D_ / 128);
    proj_gemm<<<gP, 256, 0, stream>>>(Xb, Wt, bq, bk, bv, len, qkv);

    attention<<<dim3(S_ / 64 * H_ * B_), 256, 0, stream>>>(qkv, len, out);
}

// Round 12
// 154.246 us; speedup vs baseline: 1.3084x; 1.3084x over previous
//
#include <hip/hip_runtime.h>
#include <hip/hip_bf16.h>

#define B_  2
#define S_  2048
#define D_  1024
#define H_  16
#define DK_ 64
#define M_  (B_ * S_)   // 4096

typedef short short8 __attribute__((ext_vector_type(8)));
typedef float float4v __attribute__((ext_vector_type(4)));

// log2(e)/8 : folded into Q at projection so attention exp is a bare v_exp_f32
#define QSCALE 0.18033688011112042f

static __device__ __forceinline__ ushort f32_to_bf16bits(float f) {
    union { __hip_bfloat16 h; ushort u; } cv;
    cv.h = __float2bfloat16(f);
    return cv.u;
}

// async global->LDS, 16B per lane (lands at wave-uniform base + lane*16)
static __device__ __forceinline__ void glds16(const ushort* g, ushort* l) {
    __builtin_amdgcn_global_load_lds(
        (const __attribute__((address_space(1))) unsigned int*)g,
        (__attribute__((address_space(3))) unsigned int*)l, 16, 0, 0);
}

// ---------------------------------------------------------------------------
// prep: z in [0,3) -> transpose+convert W_z[k][n] fp32 -> Wt[n][k] bf16
//       z in [3,11) -> convert X fp32 -> bf16
// ---------------------------------------------------------------------------
__global__ __launch_bounds__(256) void prep(
    const float* __restrict__ X, const float* __restrict__ W0,
    const float* __restrict__ W1, const float* __restrict__ W2,
    ushort* __restrict__ Xb, ushort* __restrict__ Wt)
{
    const int z = blockIdx.z;
    const int t = threadIdx.x;

    if (z >= 3) {   // convert X
        const int blk = (z - 3) * 256 + blockIdx.y * 16 + blockIdx.x;
        const int i = blk * 2048 + t * 8;
        float4v a = *(const float4v*)(X + i);
        float4v b = *(const float4v*)(X + i + 4);
        short8 o;
        o[0] = (short)f32_to_bf16bits(a[0]); o[1] = (short)f32_to_bf16bits(a[1]);
        o[2] = (short)f32_to_bf16bits(a[2]); o[3] = (short)f32_to_bf16bits(a[3]);
        o[4] = (short)f32_to_bf16bits(b[0]); o[5] = (short)f32_to_bf16bits(b[1]);
        o[6] = (short)f32_to_bf16bits(b[2]); o[7] = (short)f32_to_bf16bits(b[3]);
        *(short8*)(Xb + i) = o;
        return;
    }

    const float* W = (z == 0) ? W0 : ((z == 1) ? W1 : W2);
    ushort* out = Wt + (size_t)z * D_ * D_;

    __shared__ ushort tile[64 * 72];
    int n0 = blockIdx.x * 64, k0 = blockIdx.y * 64;
    int r = t >> 3, g = t & 7;

    #pragma unroll
    for (int p = 0; p < 2; ++p) {
        int rr = r + p * 32;
        const float* src = W + (size_t)(k0 + rr) * D_ + n0 + g * 8;
        float4v a = *(const float4v*)src;
        float4v b = *(const float4v*)(src + 4);
        short8 o;
        o[0] = (short)f32_to_bf16bits(a[0]); o[1] = (short)f32_to_bf16bits(a[1]);
        o[2] = (short)f32_to_bf16bits(a[2]); o[3] = (short)f32_to_bf16bits(a[3]);
        o[4] = (short)f32_to_bf16bits(b[0]); o[5] = (short)f32_to_bf16bits(b[1]);
        o[6] = (short)f32_to_bf16bits(b[2]); o[7] = (short)f32_to_bf16bits(b[3]);
        *(short8*)&tile[rr * 72 + g * 8] = o;
    }
    __syncthreads();
    #pragma unroll
    for (int p = 0; p < 2; ++p) {
        int rr = r + p * 32;
        short8 v;
        #pragma unroll
        for (int i = 0; i < 8; ++i)
            v[i] = (short)tile[(g * 8 + i) * 72 + rr];
        *(short8*)(out + (size_t)(n0 + rr) * D_ + k0 + g * 8) = v;
    }
}

// ---------------------------------------------------------------------------
// FUSED-z QKV projection: one block = (m-tile 64, n-tile 128) computing q, k
// AND v.  A staged once, 48 MFMA per barrier.  56 KB LDS = 2 blocks/CU.
// k/v work skipped (block-uniform) when this m-tile is beyond length[b].
// z==0 (Q) epilogue folds score-scale*log2(e) into the values.
// ---------------------------------------------------------------------------
__global__ __launch_bounds__(256, 2) void proj_gemm(
    const ushort* __restrict__ X,    // [4096][1024] bf16
    const ushort* __restrict__ Wt,   // [3][1024][1024] bf16, n-major
    const float* __restrict__ b0, const float* __restrict__ b1,
    const float* __restrict__ b2,
    const int* __restrict__ length,
    ushort* __restrict__ qkv)        // [3][4M] bf16
{
    const int m0 = blockIdx.x * 64, n0 = blockIdx.y * 128;
    const int bidx = m0 >> 11;
    const int s0 = m0 & (S_ - 1);
    const bool kv = (s0 < length[bidx]);   // block-uniform

    __shared__ __align__(16) ushort As[64 * 64];        //  8 KB
    __shared__ __align__(16) ushort Bs[3][128 * 64];    // 48 KB

    const int t = threadIdx.x;
    const int lane = t & 63, wid = t >> 6;
    const int quad = lane >> 4, l16 = lane & 15;
    const int wr = wid >> 1, wc = wid & 1;

    float4v accq[2][4] = {}, acck[2][4] = {}, accv[2][4] = {};

    for (int kt = 0; kt < 16; ++kt) {
        const int k0 = kt * 64;
        __syncthreads();
        #pragma unroll
        for (int j = 0; j < 2; ++j) {          // A: 512 chunks, 128/wave
            const int cid = wid * 128 + j * 64 + lane;
            const int row = cid >> 3;
            const int cl  = (cid & 7) ^ (row & 7);
            glds16(X + (size_t)(m0 + row) * D_ + k0 + cl * 8, &As[cid * 8]);
        }
        #pragma unroll
        for (int j = 0; j < 4; ++j) {          // B panels: 1024 chunks each
            const int cid = wid * 256 + j * 64 + lane;
            const int row = cid >> 3;
            const int cl  = (cid & 7) ^ (row & 7);
            const size_t off = (size_t)(n0 + row) * D_ + k0 + cl * 8;
            glds16(Wt + off, &Bs[0][cid * 8]);
            if (kv) {
                glds16(Wt + (size_t)D_ * D_ + off,     &Bs[1][cid * 8]);
                glds16(Wt + (size_t)2 * D_ * D_ + off, &Bs[2][cid * 8]);
            }
        }
        __syncthreads();

        #pragma unroll
        for (int ks = 0; ks < 2; ++ks) {
            short8 a[2];
            #pragma unroll
            for (int i = 0; i < 2; ++i) {
                const int r = wr * 32 + i * 16 + l16;
                const int ph = (ks * 4 + quad) ^ (r & 7);
                a[i] = *(short8*)&As[r * 64 + ph * 8];
            }
            short8 bq[4];
            #pragma unroll
            for (int j = 0; j < 4; ++j) {
                const int r = wc * 64 + j * 16 + l16;
                const int ph = (ks * 4 + quad) ^ (r & 7);
                bq[j] = *(short8*)&Bs[0][r * 64 + ph * 8];
            }
            #pragma unroll
            for (int i = 0; i < 2; ++i)
                #pragma unroll
                for (int j = 0; j < 4; ++j)
                    accq[i][j] = __builtin_amdgcn_mfma_f32_16x16x32_bf16(
                        a[i], bq[j], accq[i][j], 0, 0, 0);
            if (kv) {
                short8 bk[4], bv[4];
                #pragma unroll
                for (int j = 0; j < 4; ++j) {
                    const int r = wc * 64 + j * 16 + l16;
                    const int ph = (ks * 4 + quad) ^ (r & 7);
                    bk[j] = *(short8*)&Bs[1][r * 64 + ph * 8];
                    bv[j] = *(short8*)&Bs[2][r * 64 + ph * 8];
                }
                #pragma unroll
                for (int i = 0; i < 2; ++i)
                    #pragma unroll
                    for (int j = 0; j < 4; ++j) {
                        acck[i][j] = __builtin_amdgcn_mfma_f32_16x16x32_bf16(
                            a[i], bk[j], acck[i][j], 0, 0, 0);
                        accv[i][j] = __builtin_amdgcn_mfma_f32_16x16x32_bf16(
                            a[i], bv[j], accv[i][j], 0, 0, 0);
                    }
            }
        }
    }

    // epilogue: +bias, scatter into head layouts.
    #pragma unroll
    for (int j = 0; j < 4; ++j) {
        const int col = n0 + wc * 64 + j * 16 + l16;
        const int h = col >> 6, dk = col & (DK_ - 1);
        const float bvq = b0[col], bvk = b1[col], bvv = b2[col];
        #pragma unroll
        for (int i = 0; i < 2; ++i) {
            #pragma unroll
            for (int rr = 0; rr < 4; ++rr) {
                const int row = m0 + wr * 32 + i * 16 + quad * 4 + rr;
                const int s = row & (S_ - 1);
                const size_t hdr = ((size_t)(bidx * H_ + h) * S_ + s) * DK_ + dk;
                qkv[hdr] = f32_to_bf16bits((accq[i][j][rr] + bvq) * QSCALE);
                if (kv) {
                    qkv[(size_t)M_ * D_ + hdr] =
                        f32_to_bf16bits(acck[i][j][rr] + bvk);
                    qkv[(size_t)2 * M_ * D_ +
                        ((size_t)(bidx * H_ + h) * DK_ + dk) * S_ + s] =
                        f32_to_bf16bits(accv[i][j][rr] + bvv);
                }
            }
        }
    }
}

// ---------------------------------------------------------------------------
// attention v11 = v7 (register-P via PV-aligned K-row permutation, Q in regs,
// counted-vmcnt pipeline, XCD swizzle, balanced (h,b,qblk) decode, 64 q-rows,
// K/V in LDS) + ONE change: ASYMMETRIC buffering Ks[3] + Vs[2] = 40 KB.
// v10 post-mortem: per-lane global V loads scatter 64 lanes over 16 cache
// lines per instruction -> vector-memory-path bound (88 us, MfmaUtil 10%,
// FETCH unchanged 9.25MB = L2-resident, so latency wasn't the issue) -- LDS
// staging is the right structure.  Ledger: v6 {16 waves, drain}=154.0,
// v7 {12 waves, counted}=152.0; the untested corner is {16 waves, counted},
// blocked only by 48KB symmetric 3-buffers.  K needs distance-2 (consumed at
// iteration top) -> 3 buffers; V is consumed at the END (PV), so distance-1
// 2-buffer V has a full iteration + QK + exp of slack.  Per-iter schedule:
//   wait vmcnt(2) [V(kt) done; K(kt+1)'s 2 loads stay in flight; last: 0]
//   + lgkmcnt(0); s_barrier;
//   stage V(kt+1)->Vs[(kt+1)&1], K(kt+2)->Ks[(kt+2)%3]; compute.
// Issue order per iter is V then K, so at the next top the newest 2
// outstanding are K's -> vmcnt(2) clears V.  Edge cases nkt=1,2 traced.
// 40 KB = EXACTLY 4 blocks/CU -> 16 waves (4/SIMD), grid 1024 fully
// resident, same balanced decode.  Everything else identical to v7.
// ---------------------------------------------------------------------------
__global__ __launch_bounds__(256, 4) void attention(
    const ushort* __restrict__ qkv, const int* __restrict__ length,
    float* __restrict__ out)
{
    // XCD-chunk swizzle: 1024 blocks, 8 XCDs, 128 works/XCD (bijective).
    const int bid  = blockIdx.x;
    const int work = (bid & 7) * 128 + (bid >> 3);
    const int q0 = (work & 31) * 64;
    const int bh = work >> 5;          // 0..31
    const int b  = bh & 1;
    const int h  = bh >> 1;

    int len = length[b];
    if (len > S_) len = S_;
    if (len < 1) len = 1;
    const int nkt = (len + 63) >> 6;

    const ushort* qb = qkv + ((size_t)(b * H_ + h) * S_ + q0) * DK_;
    const ushort* kb = qkv + (size_t)M_ * D_ + (size_t)(b * H_ + h) * S_ * DK_;
    const ushort* vb = qkv + (size_t)2 * M_ * D_ + (size_t)(b * H_ + h) * DK_ * S_;

    __shared__ __align__(16) ushort Ks[3][64 * 64];    // 24 KB [key][dk], hash hK
    __shared__ __align__(16) ushort Vs[2][64 * 64];    // 16 KB [dk][key], hash r&7

    const int t = threadIdx.x, lane = t & 63, wid = t >> 6;
    const int quad = lane >> 4, l16 = lane & 15;

    // K read-side constants: krow = kbase[ct] + klocal; hK(krow) = hk (per-lane)
    const int klocal = ((l16 >> 2) << 3) + (l16 & 3);
    const int hk     = (l16 & 3) | (((l16 >> 2) & 1) << 2);

    // Q fragments: straight from global, no LDS.
    short8 qfrag[2];
    {
        const ushort* qp = qb + (size_t)(wid * 16 + l16) * DK_;
        qfrag[0] = *(const short8*)(qp + quad * 8);
        qfrag[1] = *(const short8*)(qp + (4 + quad) * 8);
    }

    // stage K tile / V tile (2 glds per wave each: vmcnt ticks in 2s)
    auto stageK = [&](int buf, int tile) {
        #pragma unroll
        for (int j = 0; j < 2; ++j) {
            const int cid = wid * 128 + j * 64 + lane;
            const int row = cid >> 3;
            const int c   = cid & 7;
            const int hKr = (row & 3) | (((row >> 3) & 1) << 2);
            glds16(kb + (size_t)(tile * 64 + row) * DK_ + (c ^ hKr) * 8,
                   &Ks[buf][cid * 8]);
        }
    };
    auto stageV = [&](int buf, int tile) {
        #pragma unroll
        for (int j = 0; j < 2; ++j) {
            const int cid = wid * 128 + j * 64 + lane;
            const int row = cid >> 3;
            const int c   = cid & 7;
            glds16(vb + (size_t)row * S_ + tile * 64 + (c ^ (row & 7)) * 8,
                   &Vs[buf][cid * 8]);
        }
    };

    // prologue: K(0), V(0), K(1) -- issue order matters for the counted wait.
    stageK(0, 0);
    stageV(0, 0);
    if (nkt > 1) stageK(1, 1);

    // bf16 ones fragment for the rowsum MFMA
    short8 ones8;
    #pragma unroll
    for (int i = 0; i < 8; ++i) ones8[i] = (short)0x3F80;

    float4v cacc[4] = {};
    float4v racc = {};

    int cur = 0;
    for (int kt = 0; kt < nkt; ++kt) {
        // V(kt) + K(kt) complete; the 2 newest outstanding loads are K(kt+1)
        // (issued last in the previous iteration / prologue) -- keep them in
        // flight with the counted wait.  Block-uniform branch.
        if (kt + 1 < nkt) {
            asm volatile("s_waitcnt vmcnt(2) lgkmcnt(0)" ::: "memory");
        } else {
            asm volatile("s_waitcnt vmcnt(0) lgkmcnt(0)" ::: "memory");
        }
        __builtin_amdgcn_sched_barrier(0);
        __builtin_amdgcn_s_barrier();
        __builtin_amdgcn_sched_barrier(0);

        // stage V(kt+1) FIRST, then K(kt+2) (newest), into buffers everyone
        // just finished reading (barrier above guarantees).
        if (kt + 1 < nkt) stageV((kt + 1) & 1, kt + 1);
        if (kt + 2 < nkt) {
            int sb = cur + 2; if (sb >= 3) sb -= 3;
            stageK(sb, kt + 2);
        }

        // S^T with PV-aligned K-row permutation.  Lane (quad,l16) holds
        // sacc[ct][rr] = S[key=(ct>>1)*32+quad*8+(ct&1)*4+rr][q=l16].
        float4v sacc[4] = {};
        #pragma unroll
        for (int ks = 0; ks < 2; ++ks) {
            #pragma unroll
            for (int ct = 0; ct < 4; ++ct) {
                const int krow = ((ct >> 1) << 5) + ((ct & 1) << 2) + klocal;
                const int pha = (ks * 4 + quad) ^ hk;
                short8 ak = *(short8*)&Ks[cur][krow * 64 + pha * 8];
                sacc[ct] = __builtin_amdgcn_mfma_f32_16x16x32_bf16(
                    ak, qfrag[ks], sacc[ct], 0, 0, 0);
            }
        }

        // exp2 + (boundary-only) mask + truncation-pack -> PV A-frags in regs
        const bool full = ((kt + 1) * 64 <= len);
        short8 ap[2];
        #pragma unroll
        for (int ks = 0; ks < 2; ++ks) {
            union { uint u[4]; short8 s; } cv;
            #pragma unroll
            for (int hh = 0; hh < 2; ++hh) {
                const int ct = 2 * ks + hh;
                float e0 = __builtin_amdgcn_exp2f(sacc[ct][0]);
                float e1 = __builtin_amdgcn_exp2f(sacc[ct][1]);
                float e2 = __builtin_amdgcn_exp2f(sacc[ct][2]);
                float e3 = __builtin_amdgcn_exp2f(sacc[ct][3]);
                if (!full) {
                    const int kb0 = kt * 64 + ks * 32 + quad * 8 + hh * 4;
                    e0 = (kb0 + 0 < len) ? e0 : 0.f;
                    e1 = (kb0 + 1 < len) ? e1 : 0.f;
                    e2 = (kb0 + 2 < len) ? e2 : 0.f;
                    e3 = (kb0 + 3 < len) ? e3 : 0.f;
                }
                cv.u[hh * 2 + 0] = (__float_as_uint(e0) >> 16) |
                                   (__float_as_uint(e1) & 0xFFFF0000u);
                cv.u[hh * 2 + 1] = (__float_as_uint(e2) >> 16) |
                                   (__float_as_uint(e3) & 0xFFFF0000u);
            }
            ap[ks] = cv.s;
        }

        // P @ V  (+ rowsum via ones-MFMA, reusing ap).  P never touches LDS.
        #pragma unroll
        for (int ks = 0; ks < 2; ++ks) {
            #pragma unroll
            for (int ct = 0; ct < 4; ++ct) {
                const int vrow = ct * 16 + l16;
                const int phv = (ks * 4 + quad) ^ (vrow & 7);
                short8 vv = *(short8*)&Vs[kt & 1][vrow * 64 + phv * 8];
                cacc[ct] = __builtin_amdgcn_mfma_f32_16x16x32_bf16(
                    ap[ks], vv, cacc[ct], 0, 0, 0);
            }
            racc = __builtin_amdgcn_mfma_f32_16x16x32_bf16(
                ap[ks], ones8, racc, 0, 0, 0);
        }

        cur = cur + 1; if (cur == 3) cur = 0;
    }

    // normalize + store fp32.  racc[rr] holds rowsum for q = quad*4+rr in
    // every l16 lane -- exactly where cacc[ct][rr] needs it.  No shuffles.
    #pragma unroll
    for (int rr = 0; rr < 4; ++rr) {
        const float inv = 1.0f / (racc[rr] + 1e-8f);
        const int q = q0 + wid * 16 + quad * 4 + rr;
        #pragma unroll
        for (int ct = 0; ct < 4; ++ct) {
            const int d = h * 64 + ct * 16 + l16;
            out[((size_t)b * S_ + q) * D_ + d] = cacc[ct][rr] * inv;
        }
    }
}

// ---------------------------------------------------------------------------
extern "C" void kernel_launch(void* const* d_in, const int* in_sizes, int n_in,
                              void* d_out, int out_size, void* d_ws, size_t ws_size,
                              hipStream_t stream)
{
    const float* Q   = (const float*)d_in[0];
    const int*   len = (const int*)d_in[1];
    const float* Wq  = (const float*)d_in[2];
    const float* bq  = (const float*)d_in[3];
    const float* Wk  = (const float*)d_in[4];
    const float* bk  = (const float*)d_in[5];
    const float* Wv  = (const float*)d_in[6];
    const float* bv  = (const float*)d_in[7];
    float* out = (float*)d_out;

    ushort* ws  = (ushort*)d_ws;
    ushort* Xb  = ws;                                   // 4M bf16 = 8 MB
    ushort* Wt  = ws + (size_t)M_ * D_;                 // 3M bf16 = 6 MB
    ushort* qkv = Wt + (size_t)3 * D_ * D_;             // 12M bf16 = 24 MB

    dim3 gPr(16, 16, 11);
    prep<<<gPr, 256, 0, stream>>>(Q, Wq, Wk, Wv, Xb, Wt);

    dim3 gP(M_ / 64, D_ / 128);
    proj_gemm<<<gP, 256, 0, stream>>>(Xb, Wt, bq, bk, bv, len, qkv);

    attention<<<dim3(S_ / 64 * H_ * B_), 256, 0, stream>>>(qkv, len, out);
}

// Round 13
// 152.657 us; speedup vs baseline: 1.3220x; 1.0104x over previous
//
#include <hip/hip_runtime.h>
#include <hip/hip_bf16.h>

#define B_  2
#define S_  2048
#define D_  1024
#define H_  16
#define DK_ 64
#define M_  (B_ * S_)   // 4096

typedef short short8 __attribute__((ext_vector_type(8)));
typedef float float4v __attribute__((ext_vector_type(4)));

// log2(e)/8 : folded into Q at projection so attention exp is a bare v_exp_f32
#define QSCALE 0.18033688011112042f

static __device__ __forceinline__ ushort f32_to_bf16bits(float f) {
    union { __hip_bfloat16 h; ushort u; } cv;
    cv.h = __float2bfloat16(f);
    return cv.u;
}

// async global->LDS, 16B per lane (lands at wave-uniform base + lane*16)
static __device__ __forceinline__ void glds16(const ushort* g, ushort* l) {
    __builtin_amdgcn_global_load_lds(
        (const __attribute__((address_space(1))) unsigned int*)g,
        (__attribute__((address_space(3))) unsigned int*)l, 16, 0, 0);
}

// ---------------------------------------------------------------------------
// prep: z in [0,3) -> transpose+convert W_z[k][n] fp32 -> Wt[n][k] bf16
//       z in [3,11) -> convert X fp32 -> bf16
// ---------------------------------------------------------------------------
__global__ __launch_bounds__(256) void prep(
    const float* __restrict__ X, const float* __restrict__ W0,
    const float* __restrict__ W1, const float* __restrict__ W2,
    ushort* __restrict__ Xb, ushort* __restrict__ Wt)
{
    const int z = blockIdx.z;
    const int t = threadIdx.x;

    if (z >= 3) {   // convert X
        const int blk = (z - 3) * 256 + blockIdx.y * 16 + blockIdx.x;
        const int i = blk * 2048 + t * 8;
        float4v a = *(const float4v*)(X + i);
        float4v b = *(const float4v*)(X + i + 4);
        short8 o;
        o[0] = (short)f32_to_bf16bits(a[0]); o[1] = (short)f32_to_bf16bits(a[1]);
        o[2] = (short)f32_to_bf16bits(a[2]); o[3] = (short)f32_to_bf16bits(a[3]);
        o[4] = (short)f32_to_bf16bits(b[0]); o[5] = (short)f32_to_bf16bits(b[1]);
        o[6] = (short)f32_to_bf16bits(b[2]); o[7] = (short)f32_to_bf16bits(b[3]);
        *(short8*)(Xb + i) = o;
        return;
    }

    const float* W = (z == 0) ? W0 : ((z == 1) ? W1 : W2);
    ushort* out = Wt + (size_t)z * D_ * D_;

    __shared__ ushort tile[64 * 72];
    int n0 = blockIdx.x * 64, k0 = blockIdx.y * 64;
    int r = t >> 3, g = t & 7;

    #pragma unroll
    for (int p = 0; p < 2; ++p) {
        int rr = r + p * 32;
        const float* src = W + (size_t)(k0 + rr) * D_ + n0 + g * 8;
        float4v a = *(const float4v*)src;
        float4v b = *(const float4v*)(src + 4);
        short8 o;
        o[0] = (short)f32_to_bf16bits(a[0]); o[1] = (short)f32_to_bf16bits(a[1]);
        o[2] = (short)f32_to_bf16bits(a[2]); o[3] = (short)f32_to_bf16bits(a[3]);
        o[4] = (short)f32_to_bf16bits(b[0]); o[5] = (short)f32_to_bf16bits(b[1]);
        o[6] = (short)f32_to_bf16bits(b[2]); o[7] = (short)f32_to_bf16bits(b[3]);
        *(short8*)&tile[rr * 72 + g * 8] = o;
    }
    __syncthreads();
    #pragma unroll
    for (int p = 0; p < 2; ++p) {
        int rr = r + p * 32;
        short8 v;
        #pragma unroll
        for (int i = 0; i < 8; ++i)
            v[i] = (short)tile[(g * 8 + i) * 72 + rr];
        *(short8*)(out + (size_t)(n0 + rr) * D_ + k0 + g * 8) = v;
    }
}

// ---------------------------------------------------------------------------
// FUSED-z QKV projection: one block = (m-tile 64, n-tile 128) computing q, k
// AND v.  A staged once, 48 MFMA per barrier.  56 KB LDS = 2 blocks/CU.
// k/v work skipped (block-uniform) when this m-tile is beyond length[b].
// z==0 (Q) epilogue folds score-scale*log2(e) into the values.
// At ~19 us this runs ~905 TF on its expected FLOPs = the m97-structure
// ceiling; further gains need the 256^2 8-phase rewrite (out of scope).
// ---------------------------------------------------------------------------
__global__ __launch_bounds__(256, 2) void proj_gemm(
    const ushort* __restrict__ X,    // [4096][1024] bf16
    const ushort* __restrict__ Wt,   // [3][1024][1024] bf16, n-major
    const float* __restrict__ b0, const float* __restrict__ b1,
    const float* __restrict__ b2,
    const int* __restrict__ length,
    ushort* __restrict__ qkv)        // [3][4M] bf16
{
    const int m0 = blockIdx.x * 64, n0 = blockIdx.y * 128;
    const int bidx = m0 >> 11;
    const int s0 = m0 & (S_ - 1);
    const bool kv = (s0 < length[bidx]);   // block-uniform

    __shared__ __align__(16) ushort As[64 * 64];        //  8 KB
    __shared__ __align__(16) ushort Bs[3][128 * 64];    // 48 KB

    const int t = threadIdx.x;
    const int lane = t & 63, wid = t >> 6;
    const int quad = lane >> 4, l16 = lane & 15;
    const int wr = wid >> 1, wc = wid & 1;

    float4v accq[2][4] = {}, acck[2][4] = {}, accv[2][4] = {};

    for (int kt = 0; kt < 16; ++kt) {
        const int k0 = kt * 64;
        __syncthreads();
        #pragma unroll
        for (int j = 0; j < 2; ++j) {          // A: 512 chunks, 128/wave
            const int cid = wid * 128 + j * 64 + lane;
            const int row = cid >> 3;
            const int cl  = (cid & 7) ^ (row & 7);
            glds16(X + (size_t)(m0 + row) * D_ + k0 + cl * 8, &As[cid * 8]);
        }
        #pragma unroll
        for (int j = 0; j < 4; ++j) {          // B panels: 1024 chunks each
            const int cid = wid * 256 + j * 64 + lane;
            const int row = cid >> 3;
            const int cl  = (cid & 7) ^ (row & 7);
            const size_t off = (size_t)(n0 + row) * D_ + k0 + cl * 8;
            glds16(Wt + off, &Bs[0][cid * 8]);
            if (kv) {
                glds16(Wt + (size_t)D_ * D_ + off,     &Bs[1][cid * 8]);
                glds16(Wt + (size_t)2 * D_ * D_ + off, &Bs[2][cid * 8]);
            }
        }
        __syncthreads();

        #pragma unroll
        for (int ks = 0; ks < 2; ++ks) {
            short8 a[2];
            #pragma unroll
            for (int i = 0; i < 2; ++i) {
                const int r = wr * 32 + i * 16 + l16;
                const int ph = (ks * 4 + quad) ^ (r & 7);
                a[i] = *(short8*)&As[r * 64 + ph * 8];
            }
            short8 bq[4];
            #pragma unroll
            for (int j = 0; j < 4; ++j) {
                const int r = wc * 64 + j * 16 + l16;
                const int ph = (ks * 4 + quad) ^ (r & 7);
                bq[j] = *(short8*)&Bs[0][r * 64 + ph * 8];
            }
            #pragma unroll
            for (int i = 0; i < 2; ++i)
                #pragma unroll
                for (int j = 0; j < 4; ++j)
                    accq[i][j] = __builtin_amdgcn_mfma_f32_16x16x32_bf16(
                        a[i], bq[j], accq[i][j], 0, 0, 0);
            if (kv) {
                short8 bk[4], bv[4];
                #pragma unroll
                for (int j = 0; j < 4; ++j) {
                    const int r = wc * 64 + j * 16 + l16;
                    const int ph = (ks * 4 + quad) ^ (r & 7);
                    bk[j] = *(short8*)&Bs[1][r * 64 + ph * 8];
                    bv[j] = *(short8*)&Bs[2][r * 64 + ph * 8];
                }
                #pragma unroll
                for (int i = 0; i < 2; ++i)
                    #pragma unroll
                    for (int j = 0; j < 4; ++j) {
                        acck[i][j] = __builtin_amdgcn_mfma_f32_16x16x32_bf16(
                            a[i], bk[j], acck[i][j], 0, 0, 0);
                        accv[i][j] = __builtin_amdgcn_mfma_f32_16x16x32_bf16(
                            a[i], bv[j], accv[i][j], 0, 0, 0);
                    }
            }
        }
    }

    // epilogue: +bias, scatter into head layouts.
    #pragma unroll
    for (int j = 0; j < 4; ++j) {
        const int col = n0 + wc * 64 + j * 16 + l16;
        const int h = col >> 6, dk = col & (DK_ - 1);
        const float bvq = b0[col], bvk = b1[col], bvv = b2[col];
        #pragma unroll
        for (int i = 0; i < 2; ++i) {
            #pragma unroll
            for (int rr = 0; rr < 4; ++rr) {
                const int row = m0 + wr * 32 + i * 16 + quad * 4 + rr;
                const int s = row & (S_ - 1);
                const size_t hdr = ((size_t)(bidx * H_ + h) * S_ + s) * DK_ + dk;
                qkv[hdr] = f32_to_bf16bits((accq[i][j][rr] + bvq) * QSCALE);
                if (kv) {
                    qkv[(size_t)M_ * D_ + hdr] =
                        f32_to_bf16bits(acck[i][j][rr] + bvk);
                    qkv[(size_t)2 * M_ * D_ +
                        ((size_t)(bidx * H_ + h) * DK_ + dk) * S_ + s] =
                        f32_to_bf16bits(accv[i][j][rr] + bvv);
                }
            }
        }
    }
}

// ---------------------------------------------------------------------------
// attention v7 FINAL (best measured: 152.0 us total).  Structure:
// - register-P: PV-aligned K-row permutation makes each lane's S^T output
//   exactly its PV A-fragment (krow = (ct>>1)*32 + (ct&1)*4 + klocal);
//   exp + truncation-pack in registers; P never touches LDS.  (v6: -4 us)
// - T4 counted-vmcnt: 3 LDS K/V buffers, prefetch distance 2, per-iter wait
//   vmcnt(4) (never 0 in-loop) so L2/L3 latency tails never land on the
//   barrier.  (v7: -2 us)
// - Q in registers (loop-invariant), XCD-chunk swizzle with balanced
//   (h,b,qblk) decode (FETCH 45 -> 9 MB), 64 q-rows/block, 48 KB LDS,
//   3 blocks/CU = 12 waves -- the empirically-mapped occupancy optimum
//   (8w=156.3, 12w=152.0, 16w=154.2).
// Refuted alternatives (ledger): LDS-traffic halving via 2 q-subtiles
// (v2/v8, both regimes), setprio (v9 null: 4-wave lockstep block), V via
// per-lane global loads (v10, -2.3x: 16-line scatter per instr), asymmetric
// Ks[3]+Vs[2] @ 16 waves (v11, -2 us).
// Row-sums via ones-MFMA reuse the PV A-fragment; rowsum lands in the exact
// lane that normalizes it (zero shuffles).  Q pre-scaled by log2(e)/8 at
// projection so the softmax exp is a bare v_exp_f32.  Masking only at the
// length-boundary tile; bias of truncation-pack cancels in P/sum(P).
// ---------------------------------------------------------------------------
__global__ __launch_bounds__(256, 3) void attention(
    const ushort* __restrict__ qkv, const int* __restrict__ length,
    float* __restrict__ out)
{
    // XCD-chunk swizzle: 1024 blocks, 8 XCDs, 128 works/XCD (bijective).
    // work layout: qblk fastest, then b, then h -> chunk = 4 (b,h) pairs
    // spanning BOTH batches (balanced) and only 2 distinct heads (L2-local).
    const int bid  = blockIdx.x;
    const int work = (bid & 7) * 128 + (bid >> 3);
    const int q0 = (work & 31) * 64;
    const int bh = work >> 5;          // 0..31
    const int b  = bh & 1;
    const int h  = bh >> 1;

    int len = length[b];
    if (len > S_) len = S_;
    if (len < 1) len = 1;
    const int nkt = (len + 63) >> 6;

    const ushort* qb = qkv + ((size_t)(b * H_ + h) * S_ + q0) * DK_;
    const ushort* kb = qkv + (size_t)M_ * D_ + (size_t)(b * H_ + h) * S_ * DK_;
    const ushort* vb = qkv + (size_t)2 * M_ * D_ + (size_t)(b * H_ + h) * DK_ * S_;

    __shared__ __align__(16) ushort Ks[3][64 * 64];    // 24 KB [key][dk], hash hK
    __shared__ __align__(16) ushort Vs[3][64 * 64];    // 24 KB [dk][key], hash r&7

    const int t = threadIdx.x, lane = t & 63, wid = t >> 6;
    const int quad = lane >> 4, l16 = lane & 15;

    // K read-side constants: krow = kbase[ct] + klocal; hK(krow) = hk (per-lane)
    const int klocal = ((l16 >> 2) << 3) + (l16 & 3);
    const int hk     = (l16 & 3) | (((l16 >> 2) & 1) << 2);

    // Q fragments: straight from global, no LDS.
    // B-operand layout: lane (quad,l16) holds Q[q=l16 of strip][(ks*4+quad)*8+j]
    short8 qfrag[2];
    {
        const ushort* qp = qb + (size_t)(wid * 16 + l16) * DK_;
        qfrag[0] = *(const short8*)(qp + quad * 8);
        qfrag[1] = *(const short8*)(qp + (4 + quad) * 8);
    }

    // stage K/V tile -> buffer buf (4 glds per wave: vmcnt ticks in 4s)
    auto stageKV = [&](int buf, int tile) {
        #pragma unroll
        for (int j = 0; j < 2; ++j) {
            const int cid = wid * 128 + j * 64 + lane;
            const int row = cid >> 3;
            const int c   = cid & 7;
            const int hKr = (row & 3) | (((row >> 3) & 1) << 2);
            glds16(kb + (size_t)(tile * 64 + row) * DK_ + (c ^ hKr) * 8,
                   &Ks[buf][cid * 8]);
            glds16(vb + (size_t)row * S_ + tile * 64 + (c ^ (row & 7)) * 8,
                   &Vs[buf][cid * 8]);
        }
    };

    // prologue: prefetch tiles 0 and 1
    stageKV(0, 0);
    if (nkt > 1) stageKV(1, 1);

    // bf16 ones fragment for the rowsum MFMA
    short8 ones8;
    #pragma unroll
    for (int i = 0; i < 8; ++i) ones8[i] = (short)0x3F80;

    float4v cacc[4] = {};
    float4v racc = {};

    int cur = 0;
    for (int kt = 0; kt < nkt; ++kt) {
        // own ds_reads retired + tile-kt loads complete; NEVER drain the
        // in-flight tile-kt+1 prefetch (counted vmcnt).  Block-uniform branch.
        if (kt == nkt - 1) {
            asm volatile("s_waitcnt vmcnt(0) lgkmcnt(0)" ::: "memory");
        } else {
            asm volatile("s_waitcnt vmcnt(4) lgkmcnt(0)" ::: "memory");
        }
        __builtin_amdgcn_sched_barrier(0);
        __builtin_amdgcn_s_barrier();
        __builtin_amdgcn_sched_barrier(0);

        // prefetch tile kt+2 into the buffer all waves just finished reading
        if (kt + 2 < nkt) {
            int sb = cur + 2; if (sb >= 3) sb -= 3;
            stageKV(sb, kt + 2);
        }

        // S^T with PV-aligned K-row permutation.  After this, lane (quad,l16)
        // holds sacc[ct][rr] = S[key=(ct>>1)*32+quad*8+(ct&1)*4+rr][q=l16].
        float4v sacc[4] = {};
        #pragma unroll
        for (int ks = 0; ks < 2; ++ks) {
            #pragma unroll
            for (int ct = 0; ct < 4; ++ct) {
                const int krow = ((ct >> 1) << 5) + ((ct & 1) << 2) + klocal;
                const int pha = (ks * 4 + quad) ^ hk;
                short8 ak = *(short8*)&Ks[cur][krow * 64 + pha * 8];
                sacc[ct] = __builtin_amdgcn_mfma_f32_16x16x32_bf16(
                    ak, qfrag[ks], sacc[ct], 0, 0, 0);
            }
        }

        // exp2 + (boundary-only) mask + truncation-pack -> PV A-frags in regs
        const bool full = ((kt + 1) * 64 <= len);
        short8 ap[2];
        #pragma unroll
        for (int ks = 0; ks < 2; ++ks) {
            union { uint u[4]; short8 s; } cv;
            #pragma unroll
            for (int hh = 0; hh < 2; ++hh) {
                const int ct = 2 * ks + hh;
                float e0 = __builtin_amdgcn_exp2f(sacc[ct][0]);
                float e1 = __builtin_amdgcn_exp2f(sacc[ct][1]);
                float e2 = __builtin_amdgcn_exp2f(sacc[ct][2]);
                float e3 = __builtin_amdgcn_exp2f(sacc[ct][3]);
                if (!full) {
                    const int kb0 = kt * 64 + ks * 32 + quad * 8 + hh * 4;
                    e0 = (kb0 + 0 < len) ? e0 : 0.f;
                    e1 = (kb0 + 1 < len) ? e1 : 0.f;
                    e2 = (kb0 + 2 < len) ? e2 : 0.f;
                    e3 = (kb0 + 3 < len) ? e3 : 0.f;
                }
                cv.u[hh * 2 + 0] = (__float_as_uint(e0) >> 16) |
                                   (__float_as_uint(e1) & 0xFFFF0000u);
                cv.u[hh * 2 + 1] = (__float_as_uint(e2) >> 16) |
                                   (__float_as_uint(e3) & 0xFFFF0000u);
            }
            ap[ks] = cv.s;
        }

        // P @ V  (+ rowsum via ones-MFMA, reusing ap).  P never touches LDS.
        #pragma unroll
        for (int ks = 0; ks < 2; ++ks) {
            #pragma unroll
            for (int ct = 0; ct < 4; ++ct) {
                const int vrow = ct * 16 + l16;
                const int phv = (ks * 4 + quad) ^ (vrow & 7);
                short8 vv = *(short8*)&Vs[cur][vrow * 64 + phv * 8];
                cacc[ct] = __builtin_amdgcn_mfma_f32_16x16x32_bf16(
                    ap[ks], vv, cacc[ct], 0, 0, 0);
            }
            racc = __builtin_amdgcn_mfma_f32_16x16x32_bf16(
                ap[ks], ones8, racc, 0, 0, 0);
        }

        cur = cur + 1; if (cur == 3) cur = 0;
    }

    // normalize + store fp32.  racc[rr] holds rowsum for q = quad*4+rr in
    // every l16 lane -- exactly where cacc[ct][rr] needs it.  No shuffles.
    #pragma unroll
    for (int rr = 0; rr < 4; ++rr) {
        const float inv = 1.0f / (racc[rr] + 1e-8f);
        const int q = q0 + wid * 16 + quad * 4 + rr;
        #pragma unroll
        for (int ct = 0; ct < 4; ++ct) {
            const int d = h * 64 + ct * 16 + l16;
            out[((size_t)b * S_ + q) * D_ + d] = cacc[ct][rr] * inv;
        }
    }
}

// ---------------------------------------------------------------------------
extern "C" void kernel_launch(void* const* d_in, const int* in_sizes, int n_in,
                              void* d_out, int out_size, void* d_ws, size_t ws_size,
                              hipStream_t stream)
{
    const float* Q   = (const float*)d_in[0];
    const int*   len = (const int*)d_in[1];
    const float* Wq  = (const float*)d_in[2];
    const float* bq  = (const float*)d_in[3];
    const float* Wk  = (const float*)d_in[4];
    const float* bk  = (const float*)d_in[5];
    const float* Wv  = (const float*)d_in[6];
    const float* bv  = (const float*)d_in[7];
    float* out = (float*)d_out;

    ushort* ws  = (ushort*)d_ws;
    ushort* Xb  = ws;                                   // 4M bf16 = 8 MB
    ushort* Wt  = ws + (size_t)M_ * D_;                 // 3M bf16 = 6 MB
    ushort* qkv = Wt + (size_t)3 * D_ * D_;             // 12M bf16 = 24 MB

    dim3 gPr(16, 16, 11);
    prep<<<gPr, 256, 0, stream>>>(Q, Wq, Wk, Wv, Xb, Wt);

    dim3 gP(M_ / 64, D_ / 128);
    proj_gemm<<<gP, 256, 0, stream>>>(Xb, Wt, bq, bk, bv, len, qkv);

    attention<<<dim3(S_ / 64 * H_ * B_), 256, 0, stream>>>(qkv, len, out);
}